// Round 16
// baseline (125.417 us; speedup 1.0000x reference)
//
#include <hip/hip_runtime.h>
#include <hip/hip_fp16.h>
#include <stdint.h>

// x[16384,2048] f32, w[2048,2048] f32, bias[2048] f32, scalar scales.
// M=16384, N=2048, K=2048. Output f16 values stored as f32.
#define MDIM 16384
#define NDIM 2048
#define KDIM 2048

typedef __attribute__((ext_vector_type(4))) float f32x4;
typedef __attribute__((ext_vector_type(4))) int   i32x4;
typedef __attribute__((ext_vector_type(8))) int   i32x8;

#if defined(__has_builtin)
#if __has_builtin(__builtin_amdgcn_cvt_pk_fp8_f32)
#define HAVE_CVT_PK_FP8 1
#endif
#endif

// ---------------------------------------------------------------------------
// f32 -> e4m3fn (OCP), RTNE, saturating (== clip(+-448) then cast).
// ---------------------------------------------------------------------------
__device__ __forceinline__ unsigned f32_to_e4m3(float x) {
    float q = fminf(448.f, fmaxf(-448.f, x));
    unsigned ub = __float_as_uint(q);
    unsigned sgn = (ub >> 24) & 0x80u;
    float aq = fabsf(q);
    int E = (int)((__float_as_uint(aq) >> 23) & 0xff) - 127;
    if (E < -6) E = -6;
    float rq = __uint_as_float((unsigned)(130 - E) << 23);  // 2^(3-E), exact
    int m = (int)rintf(aq * rq);                            // RTNE, exact scale
    if (m == 16) { m = 8; E += 1; }
    unsigned bits;
    if (m < 8) bits = sgn | (unsigned)m;
    else       bits = sgn | ((unsigned)(E + 7) << 3) | (unsigned)(m - 8);
    return bits;
}

__device__ __forceinline__ uint32_t pack4_e4m3(float a, float b, float c, float d) {
#ifdef HAVE_CVT_PK_FP8
    int r = __builtin_amdgcn_cvt_pk_fp8_f32(a, b, 0, false);   // bytes 0-1
    r = __builtin_amdgcn_cvt_pk_fp8_f32(c, d, r, true);        // bytes 2-3
    return (uint32_t)r;
#else
    return f32_to_e4m3(a) | (f32_to_e4m3(b) << 8) |
           (f32_to_e4m3(c) << 16) | (f32_to_e4m3(d) << 24);
#endif
}

// x-quant: linear layout.  w-quant: fragment-major packed layout Bp
// (verified r8-r15): 2048B block (n16 = col>>4, kb = ktile) holds at
// lane*32 (lane = g*16 + r15) bytes w[n16*16+r15][kb*128 + g*32 .. +31].
__global__ void quant_both_kernel(const float* __restrict__ x,
                                  uint8_t* __restrict__ xq,
                                  const float* __restrict__ w,
                                  uint8_t* __restrict__ wq,
                                  const float* __restrict__ s_in,
                                  const float* __restrict__ s_w) {
    if (blockIdx.x < 2048) {
        float sc = s_in[0];
        unsigned n16 = (unsigned)((size_t)MDIM * KDIM / 16);
        unsigned i = blockIdx.x * 256 + threadIdx.x;
        for (; i < n16; i += 2048 * 256) {
            const float4* xp = (const float4*)(x + (size_t)i * 16);
            uint32_t wd[4];
#pragma unroll
            for (int j = 0; j < 4; ++j) {
                float4 v = xp[j];
                wd[j] = pack4_e4m3(v.x / sc, v.y / sc, v.z / sc, v.w / sc);
            }
            ((uint4*)xq)[i] = make_uint4(wd[0], wd[1], wd[2], wd[3]);
        }
    } else {
        float sc = s_w[0];
        unsigned n16 = (unsigned)((size_t)NDIM * KDIM / 16);
        unsigned i = (blockIdx.x - 2048) * 256 + threadIdx.x;
        for (; i < n16; i += 256 * 256) {
            const float4* xp = (const float4*)(w + (size_t)i * 16);
            uint32_t wd[4];
#pragma unroll
            for (int j = 0; j < 4; ++j) {
                float4 v = xp[j];
                wd[j] = pack4_e4m3(v.x / sc, v.y / sc, v.z / sc, v.w / sc);
            }
            unsigned r = i >> 7, kc = i & 127;
            unsigned idx = ((r >> 4) * 16 + (kc >> 3)) * 128 +
                           ((kc & 7) >> 1) * 32 + (r & 15) * 2 + (kc & 1);
            ((uint4*)wq)[idx] = make_uint4(wd[0], wd[1], wd[2], wd[3]);
        }
    }
}

// ---------------------------------------------------------------------------
// GEMM: C = Aq * Bp^T, fp8 e4m3, mfma_scale_f32_16x16x128_f8f6f4 (unit
// scales: exact, 2x fp8 rate; verified r4-r15).
//
// Round-16: H1 test — A-DMA latency exposure.  r13/r14/r15 (three port
// mixes) all flat at ~76us => ports not binding; common trait = A staged
// 1 tile ahead, tile-end vmcnt waits its DMA (A lives in L3/thrashed L2:
// per-XCD set 8.2MB > 4MB L2; latency under load ~1500-2500cy vs ~1400cy
// cover).  Fix: TRI-BUFFERED A (3 x 16KiB) with FIFO-corrected order:
//   tile T: [af-rolling + MFMA8 x4 consuming bf(T); compiler waits
//            vmcnt(4) since bf(T) is the oldest 16 outstanding]
//           -> fence -> LOAD_BF_ALL(T+1) (16 loads, regs free after MFMAs)
//           -> fence -> STAGE_A(T+2) 4 DMA into third buffer
//           -> vmcnt(20) [outstanding: A(T+1)4 | bf(T+1)16 | A(T+2)4;
//              retires A(T+1) only] -> barrier
// A issue->wait distance: ~2 tiles (~5700cy).  bf cover ~500cy (L2 ~300).
// Entry invariant tile T: A(T) in LDS; [bf(T) 16 oldest][A(T+1) 4] in
// flight.  Prologue: A(0); bf(0); A(1); vmcnt(20); barrier.
// Geometry r14: block 128x256, 4 waves 2Mx2N, per-wave 64x128, bf direct
// from packed wq (L2), af from LDS; 2 blocks/CU (launch_bounds(256,2)).
// A chunk swizzle per 128B row: phys=(c+row)&7 (2-way residual, r4-r15).
// Epilogue: [32][256] f32 slab at lds[0] (K-loop LDS dead), 4 passes.
// ---------------------------------------------------------------------------
#define BM 128
#define BN 256
#define BKB 128
#define NKT (KDIM / BKB)   // 16

__device__ __forceinline__ void gload_lds16(const uint8_t* g, uint8_t* l) {
    __builtin_amdgcn_global_load_lds(
        (const __attribute__((address_space(1))) void*)g,
        (__attribute__((address_space(3))) void*)l, 16, 0, 0);
}

__device__ __forceinline__ void barrier_raw() {
    asm volatile("" ::: "memory");
    __builtin_amdgcn_s_barrier();
    asm volatile("" ::: "memory");
}

__global__ __launch_bounds__(256, 2) void gemm_fp8_kernel(
    const uint8_t* __restrict__ Aq, const uint8_t* __restrict__ Bp,
    const float* __restrict__ bias, const float* __restrict__ s_in,
    const float* __restrict__ s_w, float* __restrict__ out) {

    extern __shared__ uint8_t lds[];   // 49152 B: A tri-buf 3x16K; slab 32K

    // XCD-aware bijective swizzle (nwg = 1024, divisible by 8)
    int nwg = gridDim.x;
    int cpx = nwg >> 3;
    int bid = blockIdx.x;
    int swz = (bid & 7) * cpx + (bid >> 3);
    int tm = swz >> 3;                 // tiles_n = 8
    int tn = swz & 7;
    int row0 = tm * BM;
    int col0 = tn * BN;

    int tid  = threadIdx.x;
    int lane = tid & 63;
    int wid  = tid >> 6;               // 4 waves
    int wr = wid >> 1, wc = wid & 1;   // 2M x 2N, per-wave 64x128
    int r15 = lane & 15;
    int g   = lane >> 4;

    int perm0 = ((2 * g + r15) & 7) << 4;
    int perm1 = ((2 * g + 1 + r15) & 7) << 4;

    // ---- A staging: 1024 chunks/tile (128 rows x 8), 4 per thread ----
    int ssrc[4], sdst[4];
#pragma unroll
    for (int i = 0; i < 4; ++i) {
        int p = i * 256 + tid;
        int lrow = p >> 3;
        int c = ((p & 7) - (lrow & 7)) & 7;
        ssrc[i] = lrow * KDIM + c * 16;
        sdst[i] = p * 16;
    }
    const uint8_t* Asrc = Aq + (size_t)row0 * KDIM;

#define STAGE_A(KT, OFF)                                                      \
    {                                                                         \
        _Pragma("unroll")                                                     \
        for (int j_ = 0; j_ < 4; ++j_)                                        \
            gload_lds16(Asrc + ssrc[j_] + (size_t)(KT) * BKB,                 \
                        lds + (OFF) + sdst[j_]);                              \
    }

    // ---- B fragment base (packed layout; r8-r15-verified) ----
    const uint8_t* Bbase = Bp + (size_t)(tn * 16 + wc * 8) * 32768 + lane * 32;

#define LOAD_BF1(DST, N, KT)                                                  \
    {                                                                         \
        const uint8_t* p_ = Bbase + (size_t)(N) * 32768 + (size_t)(KT) * 2048; \
        i32x4 lo = *(const i32x4*)p_;                                         \
        i32x4 hi = *(const i32x4*)(p_ + 16);                                  \
        _Pragma("unroll")                                                     \
        for (int q_ = 0; q_ < 4; ++q_) { DST[q_] = lo[q_]; DST[4 + q_] = hi[q_]; } \
    }

#define LOAD_BF_ALL(KT)                                                       \
    LOAD_BF1(bf0, 0, KT); LOAD_BF1(bf1, 1, KT);                               \
    LOAD_BF1(bf2, 2, KT); LOAD_BF1(bf3, 3, KT);                               \
    LOAD_BF1(bf4, 4, KT); LOAD_BF1(bf5, 5, KT);                               \
    LOAD_BF1(bf6, 6, KT); LOAD_BF1(bf7, 7, KT);

    int aRow0 = wr * 64 + r15;         // + m*16

#define LOAD_AF1(DST, OFF, M)                                                 \
    {                                                                         \
        const uint8_t* rp = lds + (OFF) + (aRow0 + (M) * 16) * 128;           \
        i32x4 lo = *(const i32x4*)(rp + perm0);                               \
        i32x4 hi = *(const i32x4*)(rp + perm1);                               \
        _Pragma("unroll")                                                     \
        for (int q_ = 0; q_ < 4; ++q_) { DST[q_] = lo[q_]; DST[4 + q_] = hi[q_]; } \
    }

#define MFMA8(AF, M)                                                          \
    __builtin_amdgcn_s_setprio(1);                                            \
    acc[M][0] = __builtin_amdgcn_mfma_scale_f32_16x16x128_f8f6f4(             \
        AF, bf0, acc[M][0], 0, 0, 0, 127, 0, 127);                            \
    acc[M][1] = __builtin_amdgcn_mfma_scale_f32_16x16x128_f8f6f4(             \
        AF, bf1, acc[M][1], 0, 0, 0, 127, 0, 127);                            \
    acc[M][2] = __builtin_amdgcn_mfma_scale_f32_16x16x128_f8f6f4(             \
        AF, bf2, acc[M][2], 0, 0, 0, 127, 0, 127);                            \
    acc[M][3] = __builtin_amdgcn_mfma_scale_f32_16x16x128_f8f6f4(             \
        AF, bf3, acc[M][3], 0, 0, 0, 127, 0, 127);                            \
    acc[M][4] = __builtin_amdgcn_mfma_scale_f32_16x16x128_f8f6f4(             \
        AF, bf4, acc[M][4], 0, 0, 0, 127, 0, 127);                            \
    acc[M][5] = __builtin_amdgcn_mfma_scale_f32_16x16x128_f8f6f4(             \
        AF, bf5, acc[M][5], 0, 0, 0, 127, 0, 127);                            \
    acc[M][6] = __builtin_amdgcn_mfma_scale_f32_16x16x128_f8f6f4(             \
        AF, bf6, acc[M][6], 0, 0, 0, 127, 0, 127);                            \
    acc[M][7] = __builtin_amdgcn_mfma_scale_f32_16x16x128_f8f6f4(             \
        AF, bf7, acc[M][7], 0, 0, 0, 127, 0, 127);                            \
    __builtin_amdgcn_s_setprio(0);

    f32x4 acc[4][8];
#pragma unroll
    for (int m = 0; m < 4; ++m)
#pragma unroll
        for (int n = 0; n < 8; ++n)
            acc[m][n] = (f32x4){0.f, 0.f, 0.f, 0.f};

    i32x8 bf0, bf1, bf2, bf3, bf4, bf5, bf6, bf7;

    // ---- prologue: A(0); bf(0); A(1); vmcnt(20) retires A(0) only ----
    STAGE_A(0, 0u);
    asm volatile("" ::: "memory");
    LOAD_BF_ALL(0);
    asm volatile("" ::: "memory");
    STAGE_A(1, 16384u);
    asm volatile("s_waitcnt vmcnt(20)" ::: "memory");
    barrier_raw();

    unsigned offCur = 0u, offNxt = 16384u, offNN = 32768u;

    for (int t = 0; t < NKT; ++t) {
        // compute tile t: af from offCur, bf(t) in regs (oldest outstanding;
        // compiler inserts vmcnt(4) before first MFMA)
        i32x8 afE, afO;
        LOAD_AF1(afE, offCur, 0);
        LOAD_AF1(afO, offCur, 1); MFMA8(afE, 0);
        LOAD_AF1(afE, offCur, 2); MFMA8(afO, 1);
        LOAD_AF1(afO, offCur, 3); MFMA8(afE, 2);
                                  MFMA8(afO, 3);
        asm volatile("" ::: "memory");
        if (t + 1 < NKT) { LOAD_BF_ALL(t + 1); }     // 16 loads, regs free
        asm volatile("" ::: "memory");
        if (t + 2 < NKT) { STAGE_A(t + 2, offNN); }  // 4 DMA, youngest
        if (t + 2 < NKT)      asm volatile("s_waitcnt vmcnt(20)" ::: "memory");
        else if (t + 1 < NKT) asm volatile("s_waitcnt vmcnt(16)" ::: "memory");
        else                  asm volatile("s_waitcnt vmcnt(0)"  ::: "memory");
        barrier_raw();
        unsigned tmp_ = offCur; offCur = offNxt; offNxt = offNN; offNN = tmp_;
    }

    // ---- epilogue: f16 double-round + bias; [32][256] f32 slab, 4 passes --
    float s = s_in[0] * s_w[0];
    float* slab = (float*)lds;
    __half hb[8];
#pragma unroll
    for (int n = 0; n < 8; ++n)
        hb[n] = __float2half(bias[col0 + wc * 128 + n * 16 + r15]);

#pragma unroll
    for (int q = 0; q < 4; ++q) {            // out rows [q*32, q*32+32)
        if (wr == (q >> 1)) {
            const int mbase = 2 * (q & 1);
#pragma unroll
            for (int n = 0; n < 8; ++n) {
                int colb = wc * 128 + n * 16 + r15;
#pragma unroll
                for (int mm = 0; mm < 2; ++mm) {
                    int sr = mm * 16 + g * 4;
#pragma unroll
                    for (int r = 0; r < 4; ++r) {
                        __half h = __float2half(acc[mbase + mm][n][r] * s);
                        slab[(sr + r) * 256 + colb] = __half2float(__hadd(h, hb[n]));
                    }
                }
            }
        }
        barrier_raw();
        // 32 rows x 1KiB; each wave 8 rows (64 lanes x 16B per row)
#pragma unroll
        for (int it = 0; it < 8; ++it) {
            int srow = wid * 8 + it;
            f32x4 vv = *(const f32x4*)&slab[srow * 256 + lane * 4];
            int grow = row0 + q * 32 + srow;
            *(f32x4*)&out[(size_t)grow * NDIM + col0 + lane * 4] = vv;
        }
        barrier_raw();
    }
#undef STAGE_A
#undef LOAD_BF1
#undef LOAD_BF_ALL
#undef LOAD_AF1
#undef MFMA8
}

// ---------------------------------------------------------------------------
extern "C" void kernel_launch(void* const* d_in, const int* in_sizes, int n_in,
                              void* d_out, int out_size, void* d_ws, size_t ws_size,
                              hipStream_t stream) {
    const float* x      = (const float*)d_in[0];   // [16384, 2048]
    const float* weight = (const float*)d_in[1];   // [2048, 2048]
    const float* bias   = (const float*)d_in[2];   // [2048]
    const float* s_in   = (const float*)d_in[3];   // [1]
    const float* s_w    = (const float*)d_in[4];   // [1]
    float* out          = (float*)d_out;

    uint8_t* xq = (uint8_t*)d_ws;                          // 33.5 MB (linear)
    uint8_t* wq = (uint8_t*)d_ws + (size_t)MDIM * KDIM;    // 4.2 MB (packed)

    quant_both_kernel<<<2304, 256, 0, stream>>>(x, xq, weight, wq, s_in, s_w);

    dim3 grid((MDIM / BM) * (NDIM / BN));   // 128 * 8 = 1024
    gemm_fp8_kernel<<<grid, 256, 49152, stream>>>(xq, wq, bias, s_in, s_w, out);
}

// Round 17
// 111.484 us; speedup vs baseline: 1.1250x; 1.1250x over previous
//
#include <hip/hip_runtime.h>
#include <hip/hip_fp16.h>
#include <stdint.h>

// x[16384,2048] f32, w[2048,2048] f32, bias[2048] f32, scalar scales.
// M=16384, N=2048, K=2048. Output f16 values stored as f32.
#define MDIM 16384
#define NDIM 2048
#define KDIM 2048

typedef __attribute__((ext_vector_type(4))) float f32x4;
typedef __attribute__((ext_vector_type(4))) int   i32x4;
typedef __attribute__((ext_vector_type(8))) int   i32x8;

#if defined(__has_builtin)
#if __has_builtin(__builtin_amdgcn_cvt_pk_fp8_f32)
#define HAVE_CVT_PK_FP8 1
#endif
#endif

// ---------------------------------------------------------------------------
// f32 -> e4m3fn (OCP), RTNE, saturating (== clip(+-448) then cast).
// ---------------------------------------------------------------------------
__device__ __forceinline__ unsigned f32_to_e4m3(float x) {
    float q = fminf(448.f, fmaxf(-448.f, x));
    unsigned ub = __float_as_uint(q);
    unsigned sgn = (ub >> 24) & 0x80u;
    float aq = fabsf(q);
    int E = (int)((__float_as_uint(aq) >> 23) & 0xff) - 127;
    if (E < -6) E = -6;
    float rq = __uint_as_float((unsigned)(130 - E) << 23);  // 2^(3-E), exact
    int m = (int)rintf(aq * rq);                            // RTNE, exact scale
    if (m == 16) { m = 8; E += 1; }
    unsigned bits;
    if (m < 8) bits = sgn | (unsigned)m;
    else       bits = sgn | ((unsigned)(E + 7) << 3) | (unsigned)(m - 8);
    return bits;
}

__device__ __forceinline__ uint32_t pack4_e4m3(float a, float b, float c, float d) {
#ifdef HAVE_CVT_PK_FP8
    int r = __builtin_amdgcn_cvt_pk_fp8_f32(a, b, 0, false);   // bytes 0-1
    r = __builtin_amdgcn_cvt_pk_fp8_f32(c, d, r, true);        // bytes 2-3
    return (uint32_t)r;
#else
    return f32_to_e4m3(a) | (f32_to_e4m3(b) << 8) |
           (f32_to_e4m3(c) << 16) | (f32_to_e4m3(d) << 24);
#endif
}

// x-quant: linear layout.  w-quant: fragment-major packed layout Bp
// (verified r8-r16): 2048B block (n16 = col>>4, kb = ktile) holds at
// lane*32 (lane = g*16 + r15) bytes w[n16*16+r15][kb*128 + g*32 .. +31].
__global__ void quant_both_kernel(const float* __restrict__ x,
                                  uint8_t* __restrict__ xq,
                                  const float* __restrict__ w,
                                  uint8_t* __restrict__ wq,
                                  const float* __restrict__ s_in,
                                  const float* __restrict__ s_w) {
    if (blockIdx.x < 2048) {
        float sc = s_in[0];
        unsigned n16 = (unsigned)((size_t)MDIM * KDIM / 16);
        unsigned i = blockIdx.x * 256 + threadIdx.x;
        for (; i < n16; i += 2048 * 256) {
            const float4* xp = (const float4*)(x + (size_t)i * 16);
            uint32_t wd[4];
#pragma unroll
            for (int j = 0; j < 4; ++j) {
                float4 v = xp[j];
                wd[j] = pack4_e4m3(v.x / sc, v.y / sc, v.z / sc, v.w / sc);
            }
            ((uint4*)xq)[i] = make_uint4(wd[0], wd[1], wd[2], wd[3]);
        }
    } else {
        float sc = s_w[0];
        unsigned n16 = (unsigned)((size_t)NDIM * KDIM / 16);
        unsigned i = (blockIdx.x - 2048) * 256 + threadIdx.x;
        for (; i < n16; i += 256 * 256) {
            const float4* xp = (const float4*)(w + (size_t)i * 16);
            uint32_t wd[4];
#pragma unroll
            for (int j = 0; j < 4; ++j) {
                float4 v = xp[j];
                wd[j] = pack4_e4m3(v.x / sc, v.y / sc, v.z / sc, v.w / sc);
            }
            unsigned r = i >> 7, kc = i & 127;
            unsigned idx = ((r >> 4) * 16 + (kc >> 3)) * 128 +
                           ((kc & 7) >> 1) * 32 + (r & 15) * 2 + (kc & 1);
            ((uint4*)wq)[idx] = make_uint4(wd[0], wd[1], wd[2], wd[3]);
        }
    }
}

// ---------------------------------------------------------------------------
// GEMM: C = Aq * Bp^T, fp8 e4m3, mfma_scale_f32_16x16x128_f8f6f4 (unit
// scales: exact, 2x fp8 rate; verified r4-r16).
//
// Round-17: N-OUTER MFMA order (single change vs r14; r16's tri-buffer
// reverted).  r13-r16's m-outer MFMA8 consumed ALL 8 bf frags in the first
// MFMA -> compiler's wait drained the whole 16-load bf batch at ~300cy
// issue->use distance: a full L2-latency stall, batch-wide, every tile,
// every wave.  n-outer (hold all 4 af; burst 4 MFMAs per bf frag) makes the
// per-register counted waits PROGRESSIVE: bf0 vmcnt(18)@~300cy (marginal),
// bf1 vmcnt(16)@~440cy, ... bf7 vmcnt(4)@~1270cy (ample) - AITER's
// "counted, never 0" pattern arising from program order.
//
// Geometry (r14, proven): block 128x256, 4 waves 2Mx2N, per-wave 64x128,
// bf direct from packed wq (L2-resident), af via LDS dbuf 2x16KiB,
// 2 blocks/CU (launch_bounds(256,2)).
// FIFO per tile t: entry [bf(t) 16]; STAGE_A(t+1) 4 -> 20; MFMA bursts
// retire bf progressively; LOAD_BF_ALL(t+1) -> (rest + 16); vmcnt(16)
// retires A(t+1); barrier.  Regs: af 32 + bf 64 + addr ~32 (VGPR ~128)
// + acc 128 AGPR.  Spill tripwire: FETCH > 60MB.
// A chunk swizzle per 128B row: phys=(c+row)&7 (2-way residual, r4-r16).
// Epilogue: [32][256] f32 slab, 4 passes, 1KiB dwordx4 rows (r14).
// ---------------------------------------------------------------------------
#define BM 128
#define BN 256
#define BKB 128
#define NKT (KDIM / BKB)   // 16

__device__ __forceinline__ void gload_lds16(const uint8_t* g, uint8_t* l) {
    __builtin_amdgcn_global_load_lds(
        (const __attribute__((address_space(1))) void*)g,
        (__attribute__((address_space(3))) void*)l, 16, 0, 0);
}

__device__ __forceinline__ void barrier_raw() {
    asm volatile("" ::: "memory");
    __builtin_amdgcn_s_barrier();
    asm volatile("" ::: "memory");
}

__global__ __launch_bounds__(256, 2) void gemm_fp8_kernel(
    const uint8_t* __restrict__ Aq, const uint8_t* __restrict__ Bp,
    const float* __restrict__ bias, const float* __restrict__ s_in,
    const float* __restrict__ s_w, float* __restrict__ out) {

    extern __shared__ uint8_t lds[];   // 32768 B: 2 x 16KiB A-dbuf / slab

    // XCD-aware bijective swizzle (nwg = 1024, divisible by 8)
    int nwg = gridDim.x;
    int cpx = nwg >> 3;
    int bid = blockIdx.x;
    int swz = (bid & 7) * cpx + (bid >> 3);
    int tm = swz >> 3;                 // tiles_n = 8
    int tn = swz & 7;
    int row0 = tm * BM;
    int col0 = tn * BN;

    int tid  = threadIdx.x;
    int lane = tid & 63;
    int wid  = tid >> 6;               // 4 waves
    int wr = wid >> 1, wc = wid & 1;   // 2M x 2N, per-wave 64x128
    int r15 = lane & 15;
    int g   = lane >> 4;

    int perm0 = ((2 * g + r15) & 7) << 4;
    int perm1 = ((2 * g + 1 + r15) & 7) << 4;

    // ---- A staging: 1024 chunks/tile (128 rows x 8), 4 per thread ----
    int ssrc[4], sdst[4];
#pragma unroll
    for (int i = 0; i < 4; ++i) {
        int p = i * 256 + tid;
        int lrow = p >> 3;
        int c = ((p & 7) - (lrow & 7)) & 7;
        ssrc[i] = lrow * KDIM + c * 16;
        sdst[i] = p * 16;
    }
    const uint8_t* Asrc = Aq + (size_t)row0 * KDIM;

#define STAGE_A(KT, BUF)                                                      \
    {                                                                         \
        _Pragma("unroll")                                                     \
        for (int j_ = 0; j_ < 4; ++j_)                                        \
            gload_lds16(Asrc + ssrc[j_] + (size_t)(KT) * BKB, (BUF) + sdst[j_]); \
    }

    // ---- B fragment base (packed layout; r8-r16-verified) ----
    const uint8_t* Bbase = Bp + (size_t)(tn * 16 + wc * 8) * 32768 + lane * 32;

#define LOAD_BF1(DST, N, KT)                                                  \
    {                                                                         \
        const uint8_t* p_ = Bbase + (size_t)(N) * 32768 + (size_t)(KT) * 2048; \
        i32x4 lo = *(const i32x4*)p_;                                         \
        i32x4 hi = *(const i32x4*)(p_ + 16);                                  \
        _Pragma("unroll")                                                     \
        for (int q_ = 0; q_ < 4; ++q_) { DST[q_] = lo[q_]; DST[4 + q_] = hi[q_]; } \
    }

    // issue order 0..7 => FIFO age order matches burst order (progressive waits)
#define LOAD_BF_ALL(KT)                                                       \
    LOAD_BF1(bf0, 0, KT); LOAD_BF1(bf1, 1, KT);                               \
    LOAD_BF1(bf2, 2, KT); LOAD_BF1(bf3, 3, KT);                               \
    LOAD_BF1(bf4, 4, KT); LOAD_BF1(bf5, 5, KT);                               \
    LOAD_BF1(bf6, 6, KT); LOAD_BF1(bf7, 7, KT);

    int aRow0 = wr * 64 + r15;         // + m*16

#define LOAD_AF1(DST, bo, M)                                                  \
    {                                                                         \
        const uint8_t* rp = lds + (bo) + (aRow0 + (M) * 16) * 128;            \
        i32x4 lo = *(const i32x4*)(rp + perm0);                               \
        i32x4 hi = *(const i32x4*)(rp + perm1);                               \
        _Pragma("unroll")                                                     \
        for (int q_ = 0; q_ < 4; ++q_) { DST[q_] = lo[q_]; DST[4 + q_] = hi[q_]; } \
    }

    // n-outer burst: 4 MFMAs (af0..af3) against one bf fragment
#define MFMA4N(BF, N)                                                         \
    __builtin_amdgcn_s_setprio(1);                                            \
    acc[0][N] = __builtin_amdgcn_mfma_scale_f32_16x16x128_f8f6f4(             \
        af0, BF, acc[0][N], 0, 0, 0, 127, 0, 127);                            \
    acc[1][N] = __builtin_amdgcn_mfma_scale_f32_16x16x128_f8f6f4(             \
        af1, BF, acc[1][N], 0, 0, 0, 127, 0, 127);                            \
    acc[2][N] = __builtin_amdgcn_mfma_scale_f32_16x16x128_f8f6f4(             \
        af2, BF, acc[2][N], 0, 0, 0, 127, 0, 127);                            \
    acc[3][N] = __builtin_amdgcn_mfma_scale_f32_16x16x128_f8f6f4(             \
        af3, BF, acc[3][N], 0, 0, 0, 127, 0, 127);                            \
    __builtin_amdgcn_s_setprio(0);

    f32x4 acc[4][8];
#pragma unroll
    for (int m = 0; m < 4; ++m)
#pragma unroll
        for (int n = 0; n < 8; ++n)
            acc[m][n] = (f32x4){0.f, 0.f, 0.f, 0.f};

    i32x8 bf0, bf1, bf2, bf3, bf4, bf5, bf6, bf7;
    i32x8 af0, af1, af2, af3;

    uint8_t* buf0 = &lds[0];
    uint8_t* buf1 = &lds[16384];

    // ---- prologue: stage A(0) [4 DMA]; bf(0) [16 loads];
    //      vmcnt(16) drains DMA, leaves bf(0) in flight; barrier ----
    STAGE_A(0, buf0);
    asm volatile("" ::: "memory");     // pin DMA before bf in VMEM FIFO
    LOAD_BF_ALL(0);
    asm volatile("s_waitcnt vmcnt(16)" ::: "memory");
    barrier_raw();

    // Entry invariant tile T: bf(T) 16 in flight (oldest), A(T) landed.
#define TILE_BODY(T)                                                          \
    {                                                                         \
        const unsigned bo = ((unsigned)(T) & 1) << 14;                        \
        uint8_t* nxt_ = (((T) & 1) ? buf0 : buf1);                            \
        if ((T) + 1 < NKT) STAGE_A((T) + 1, nxt_);   /* 4 DMA after bf(T) */  \
        asm volatile("" ::: "memory");                                        \
        LOAD_AF1(af0, bo, 0); LOAD_AF1(af1, bo, 1);                           \
        LOAD_AF1(af2, bo, 2); LOAD_AF1(af3, bo, 3);                           \
        MFMA4N(bf0, 0);      /* compiler: vmcnt(18) - only bf0 needed */      \
        MFMA4N(bf1, 1);      /* vmcnt(16) */                                  \
        MFMA4N(bf2, 2);      /* vmcnt(14) ... progressive */                  \
        MFMA4N(bf3, 3);                                                       \
        MFMA4N(bf4, 4);                                                       \
        MFMA4N(bf5, 5);                                                       \
        MFMA4N(bf6, 6);                                                       \
        MFMA4N(bf7, 7);      /* vmcnt(4) at ~1270cy distance */               \
        if ((T) + 1 < NKT) {                                                  \
            asm volatile("" ::: "memory");                                    \
            LOAD_BF_ALL((T) + 1);          /* 16 loads, regs now free */      \
            asm volatile("s_waitcnt vmcnt(16)" ::: "memory"); /* A(T+1) in */ \
        } else {                                                              \
            asm volatile("s_waitcnt vmcnt(0)" ::: "memory");                  \
        }                                                                     \
        barrier_raw();                                                        \
    }

    for (int t = 0; t < NKT; ++t)
        TILE_BODY(t);

    // ---- epilogue: f16 double-round + bias; [32][256] f32 slab, 4 passes --
    float s = s_in[0] * s_w[0];
    float* slab = (float*)lds;
    __half hb[8];
#pragma unroll
    for (int n = 0; n < 8; ++n)
        hb[n] = __float2half(bias[col0 + wc * 128 + n * 16 + r15]);

#pragma unroll
    for (int q = 0; q < 4; ++q) {            // out rows [q*32, q*32+32)
        if (wr == (q >> 1)) {
            const int mbase = 2 * (q & 1);
#pragma unroll
            for (int n = 0; n < 8; ++n) {
                int colb = wc * 128 + n * 16 + r15;
#pragma unroll
                for (int mm = 0; mm < 2; ++mm) {
                    int sr = mm * 16 + g * 4;
#pragma unroll
                    for (int r = 0; r < 4; ++r) {
                        __half h = __float2half(acc[mbase + mm][n][r] * s);
                        slab[(sr + r) * 256 + colb] = __half2float(__hadd(h, hb[n]));
                    }
                }
            }
        }
        barrier_raw();
        // 32 rows x 1KiB; each wave 8 rows (64 lanes x 16B per row)
#pragma unroll
        for (int it = 0; it < 8; ++it) {
            int srow = wid * 8 + it;
            f32x4 vv = *(const f32x4*)&slab[srow * 256 + lane * 4];
            int grow = row0 + q * 32 + srow;
            *(f32x4*)&out[(size_t)grow * NDIM + col0 + lane * 4] = vv;
        }
        barrier_raw();
    }
#undef STAGE_A
#undef LOAD_BF1
#undef LOAD_BF_ALL
#undef LOAD_AF1
#undef MFMA4N
#undef TILE_BODY
}

// ---------------------------------------------------------------------------
extern "C" void kernel_launch(void* const* d_in, const int* in_sizes, int n_in,
                              void* d_out, int out_size, void* d_ws, size_t ws_size,
                              hipStream_t stream) {
    const float* x      = (const float*)d_in[0];   // [16384, 2048]
    const float* weight = (const float*)d_in[1];   // [2048, 2048]
    const float* bias   = (const float*)d_in[2];   // [2048]
    const float* s_in   = (const float*)d_in[3];   // [1]
    const float* s_w    = (const float*)d_in[4];   // [1]
    float* out          = (float*)d_out;

    uint8_t* xq = (uint8_t*)d_ws;                          // 33.5 MB (linear)
    uint8_t* wq = (uint8_t*)d_ws + (size_t)MDIM * KDIM;    // 4.2 MB (packed)

    quant_both_kernel<<<2304, 256, 0, stream>>>(x, xq, weight, wq, s_in, s_w);

    dim3 grid((MDIM / BM) * (NDIM / BN));   // 128 * 8 = 1024
    gemm_fp8_kernel<<<grid, 256, 32768, stream>>>(xq, wq, bias, s_in, s_w, out);
}